// Round 9
// baseline (63.087 us; speedup 1.0000x reference)
//
#include <hip/hip_runtime.h>

// NetVLAD fused via bf16 MFMA, two-stage, 8-wave blocks, pipelined staging.
//   s = x·W  (per-pixel 1x1 conv), a = softmax_k(s), v = a^T x + (sum a)·C
// x: [64,784,512] f32, W/C: [512,32] f32, out: [64, 512*32] f32
#define NB 64
#define HW 784
#define DD 512
#define KK 32
#define BPB 8             // blocks per batch: 512 blocks = exactly 2/CU
#define PPB 98            // pixels per block
#define CHUNK 32          // pixels per chunk slot
#define NCHUNK 4          // valid px per chunk: 32,32,32,2 (rest a=0)

typedef __attribute__((ext_vector_type(8))) short bf16x8;   // 8 bf16 (4 VGPR)
typedef __attribute__((ext_vector_type(4))) float f32x4;    // MFMA 16x16 acc

// ws: partials [NB*BPB][8 waves][8 frags][64 lanes] float4, then asums [NB*BPB][KK]
#define PART_F   ((size_t)NB * BPB * 8 * 8 * 64 * 4)
#define ASUM_OFF PART_F
#define WS_NEED  ((PART_F + (size_t)NB * BPB * KK) * sizeof(float))

__device__ __forceinline__ unsigned short f2bf(float f) {
    unsigned u = __float_as_uint(f);
    u += 0x7fffu + ((u >> 16) & 1u);      // round-to-nearest-even
    return (unsigned short)(u >> 16);
}

template <bool USE_WS>
__global__ __launch_bounds__(512) void netvlad_stage1(
    const float* __restrict__ x, const float* __restrict__ Wg,
    const float* __restrict__ Cg, float* __restrict__ out,
    float* __restrict__ ws)
{
    // LDS total ~51.6 KB -> 2 blocks/CU (16 waves/CU)
    __shared__ __align__(16) unsigned short xs[CHUNK * 520];   // 33.3 KB bf16 chunk
    __shared__ float spart[4][CHUNK][33];                      // 16.9 KB d-split partials
    __shared__ __align__(16) unsigned short aTe[KK * 40];      // a^T [k][px] (2.56 KB)
    __shared__ float asumF[KK];

    const int tid = threadIdx.x;
    const int l   = tid & 63, w = tid >> 6;      // lane, wave 0..7
    const int l15 = l & 15,  lq = l >> 4;        // frag row/col, quarter
    const int d4  = w & 3;                        // phase-A d-slice 128*d4
    const int pgrp= w >> 2;                       // phase-A px-group (16 px)
    const int k   = tid & 31, pg = tid >> 5;     // softmax mapping: pg 0..15
    const int bid = blockIdx.x;
    const int b   = bid / BPB;
    const int pb  = (bid % BPB) * PPB;
    const float* xb = x + (size_t)b * HW * DD;

    // W B-frags: Wf[ks][nt] lane holds W[d = d4*128+ks*32+lq*8+j][nt*16+l15]
    bf16x8 Wf[4][2];
#pragma unroll
    for (int ks = 0; ks < 4; ++ks)
#pragma unroll
        for (int nt = 0; nt < 2; ++nt)
#pragma unroll
            for (int j = 0; j < 8; ++j)
                Wf[ks][nt][j] = (short)f2bf(Wg[(d4*128 + ks*32 + lq*8 + j) * KK + nt*16 + l15]);

    // phase-C: wave owns d-slice [64w, 64w+64): acc[mt][nt] -> k=mt*16+lq*4+jj, d=64w+nt*16+l15
    f32x4 acc[2][4];
#pragma unroll
    for (int mt = 0; mt < 2; ++mt)
#pragma unroll
        for (int nt = 0; nt < 4; ++nt)
#pragma unroll
            for (int jj = 0; jj < 4; ++jj) acc[mt][nt][jj] = 0.f;
    float asum_part = 0.f;

    // T14 split staging: issue loads early (r[8] = 32 VGPR held), commit late.
    float4 r[8];
    auto stageLoad = [&](int c) {
#pragma unroll
        for (int j = 0; j < 8; ++j) {
            const int f = tid + 512*j, row = f >> 7, c4 = f & 127;
            const int p = c*CHUNK + row;
            const int gp = pb + (p < PPB ? p : PPB - 1);   // clamp pad rows (L2 hit)
            r[j] = *(const float4*)(xb + (size_t)gp * DD + c4*4);
        }
    };
    auto stageCommit = [&]() {
#pragma unroll
        for (int j = 0; j < 8; ++j) {
            const int f = tid + 512*j, row = f >> 7, c4 = f & 127;
            uint2 pk = make_uint2((unsigned)f2bf(r[j].x) | ((unsigned)f2bf(r[j].y) << 16),
                                  (unsigned)f2bf(r[j].z) | ((unsigned)f2bf(r[j].w) << 16));
            *(uint2*)&xs[row*520 + c4*4] = pk;
        }
    };

    stageLoad(0);
    stageCommit();
    __syncthreads();

    for (int c = 0; c < NCHUNK; ++c) {
        if (c + 1 < NCHUNK) stageLoad(c + 1);   // flies during phases A/B/C

        // ---- phase A: s[16px(pgrp)][32k] partial over d-slice 128*d4 ----
        f32x4 sp[2];
#pragma unroll
        for (int nt = 0; nt < 2; ++nt)
#pragma unroll
            for (int jj = 0; jj < 4; ++jj) sp[nt][jj] = 0.f;
#pragma unroll
        for (int ks = 0; ks < 4; ++ks) {
            const bf16x8 af = *(const bf16x8*)&xs[(pgrp*16 + l15)*520 + d4*128 + ks*32 + lq*8];
#pragma unroll
            for (int nt = 0; nt < 2; ++nt)
                sp[nt] = __builtin_amdgcn_mfma_f32_16x16x32_bf16(
                    af, Wf[ks][nt], sp[nt], 0, 0, 0);
        }
#pragma unroll
        for (int nt = 0; nt < 2; ++nt)
#pragma unroll
            for (int jj = 0; jj < 4; ++jj)
                spart[d4][pgrp*16 + lq*4 + jj][nt*16 + l15] = sp[nt][jj];
        __syncthreads();

        // ---- phase B: softmax over k; thread (pg,k), px = pg + 16i ----
        const int valid = (PPB - c*CHUNK < CHUNK) ? (PPB - c*CHUNK) : CHUNK;
#pragma unroll
        for (int i = 0; i < 2; ++i) {
            const int p = pg + 16*i;
            const float s = spart[0][p][k] + spart[1][p][k]
                          + spart[2][p][k] + spart[3][p][k];
            const float e = __expf(s);
            float su = e;
#pragma unroll
            for (int msk = 16; msk >= 1; msk >>= 1)
                su += __shfl_xor(su, msk);
            const float a = (p < valid) ? e * __builtin_amdgcn_rcpf(su) : 0.f;
            asum_part += a;
            aTe[k*40 + p] = f2bf(a);
        }
        __syncthreads();

        // ---- phase C: v^T[32k][64d-slice] += a^T[32k][32px] · x[32px][d] ----
        bf16x8 afr[2];
#pragma unroll
        for (int mt = 0; mt < 2; ++mt)
            afr[mt] = *(const bf16x8*)&aTe[(mt*16 + l15)*40 + lq*8];
#pragma unroll
        for (int nt = 0; nt < 4; ++nt) {
            const int d = w*64 + nt*16 + l15;
            bf16x8 bfr;
#pragma unroll
            for (int j = 0; j < 8; ++j) {                  // column read of x, j rotated
                const int jj = (j + 2*lq) & 7;             // per-quarter bank stagger
                bfr[jj] = (short)xs[(lq*8 + jj)*520 + d];
            }
#pragma unroll
            for (int mt = 0; mt < 2; ++mt)
                acc[mt][nt] = __builtin_amdgcn_mfma_f32_16x16x32_bf16(
                    afr[mt], bfr, acc[mt][nt], 0, 0, 0);
        }
        __syncthreads();

        if (c + 1 < NCHUNK) {       // xs free after phase C's barrier; loads landed
            stageCommit();
            __syncthreads();
        }
    }

    // ---- block asum[k] reduce (ared aliases aTe: dead after last phase C) ----
    float* ared = (float*)aTe;     // [16][32]
    ared[pg*KK + k] = asum_part;
    __syncthreads();
    if (tid < KK) {
        float s = 0.f;
#pragma unroll
        for (int g = 0; g < 16; ++g) s += ared[g*KK + tid];
        if (USE_WS) ws[ASUM_OFF + (size_t)bid * KK + tid] = s;
        else        asumF[tid] = s;
    }

    if (USE_WS) {
        // partial store, thread-major: fully coalesced float4 streaming
        float4* o = (float4*)ws + ((size_t)bid * 8 + w) * (8 * 64);
#pragma unroll
        for (int mt = 0; mt < 2; ++mt)
#pragma unroll
            for (int nt = 0; nt < 4; ++nt)
                o[(mt*4 + nt)*64 + l] = make_float4(acc[mt][nt][0], acc[mt][nt][1],
                                                    acc[mt][nt][2], acc[mt][nt][3]);
    } else {
        __syncthreads();
        float* ob = out + (size_t)b * (DD * KK);
#pragma unroll
        for (int mt = 0; mt < 2; ++mt)
#pragma unroll
            for (int nt = 0; nt < 4; ++nt)
#pragma unroll
                for (int jj = 0; jj < 4; ++jj) {
                    const int kk = mt*16 + lq*4 + jj;
                    const int d  = w*64 + nt*16 + l15;
                    atomicAdd(&ob[d*KK + kk], acc[mt][nt][jj] + asumF[kk] * Cg[d*KK + kk]);
                }
    }
}

// Stage 2: block = (b, 128-d slice): sum 8 partials, add asum_total*C, write canonical
__global__ __launch_bounds__(256) void netvlad_stage2(
    const float* __restrict__ ws, const float* __restrict__ Cg,
    float* __restrict__ out)
{
    __shared__ float lds[128 * 33];    // canonical [d_local][k], padded
    __shared__ float asumT[KK];

    const int t = threadIdx.x;
    const int b = blockIdx.x >> 2;
    const int jsl = blockIdx.x & 3;    // d-slice [128*jsl, +128) = stage1 waves {2jsl, 2jsl+1}

    if (t < KK) {
        float s = 0.f;
#pragma unroll
        for (int p = 0; p < BPB; ++p)
            s += ws[ASUM_OFF + (size_t)(b*BPB + p) * KK + t];
        asumT[t] = s;
    }

    const float4* wsp = (const float4*)ws;
    float4 v[4];
#pragma unroll
    for (int i = 0; i < 4; ++i) v[i] = make_float4(0.f, 0.f, 0.f, 0.f);
    for (int p = 0; p < BPB; ++p) {
        const size_t base = (size_t)(b*BPB + p) * 8 * (8 * 64);
#pragma unroll
        for (int i = 0; i < 4; ++i) {
            const int flat = t + 256*i;           // (w2, fr, lane)
            const int g = flat >> 6, lane = flat & 63;
            const int w2 = g >> 3, fr = g & 7;
            const float4 f4 = wsp[base + ((size_t)(2*jsl + w2) * 8 + fr)*64 + lane];
            v[i].x += f4.x; v[i].y += f4.y; v[i].z += f4.z; v[i].w += f4.w;
        }
    }
    // scatter frag layout -> canonical [d_local][k]
#pragma unroll
    for (int i = 0; i < 4; ++i) {
        const int flat = t + 256*i;
        const int g = flat >> 6, lane = flat & 63;
        const int w2 = g >> 3, fr = g & 7;
        const int mt = fr >> 2, nt = fr & 3;
        const int q = lane >> 4, r15 = lane & 15;
        const int dl = w2*64 + nt*16 + r15;
        const int kb = mt*16 + q*4;
        lds[dl*33 + kb + 0] = v[i].x;
        lds[dl*33 + kb + 1] = v[i].y;
        lds[dl*33 + kb + 2] = v[i].z;
        lds[dl*33 + kb + 3] = v[i].w;
    }
    __syncthreads();

    float* outw = out + (size_t)b * (DD*KK) + jsl * 128 * KK;
    const float* Cw = Cg + jsl * 128 * KK;
#pragma unroll
    for (int i = 0; i < 4; ++i) {
        const int o4 = t + 256*i;
        const int dl = o4 >> 3, kq = (o4 & 7) * 4;
        const float4 c4 = *(const float4*)&Cw[dl*KK + kq];
        float4 rr;
        rr.x = lds[dl*33 + kq + 0] + asumT[kq + 0] * c4.x;
        rr.y = lds[dl*33 + kq + 1] + asumT[kq + 1] * c4.y;
        rr.z = lds[dl*33 + kq + 2] + asumT[kq + 2] * c4.z;
        rr.w = lds[dl*33 + kq + 3] + asumT[kq + 3] * c4.w;
        ((float4*)outw)[o4] = rr;
    }
}

extern "C" void kernel_launch(void* const* d_in, const int* in_sizes, int n_in,
                              void* d_out, int out_size, void* d_ws, size_t ws_size,
                              hipStream_t stream) {
    const float* x = (const float*)d_in[0];
    const float* W = (const float*)d_in[1];
    const float* C = (const float*)d_in[2];
    float* out = (float*)d_out;

    if (ws_size >= WS_NEED) {
        float* ws = (float*)d_ws;
        netvlad_stage1<true><<<dim3(NB * BPB), dim3(512), 0, stream>>>(x, W, C, out, ws);
        netvlad_stage2<<<dim3(NB * 4), dim3(256), 0, stream>>>(ws, C, out);
    } else {
        hipMemsetAsync(out, 0, (size_t)out_size * sizeof(float), stream);
        netvlad_stage1<false><<<dim3(NB * BPB), dim3(512), 0, stream>>>(x, W, C, out, nullptr);
    }
}

// Round 10
// 59.216 us; speedup vs baseline: 1.0654x; 1.0654x over previous
//
#include <hip/hip_runtime.h>

// NetVLAD fused via bf16 MFMA, two-stage, 8-wave blocks.
// Staging = global_load_lds DMA (fp32 in LDS, no VGPR round-trip, no convert VALU);
// bf16 conversion happens at fragment-build time in phases A/C.
//   s = x·W, a = softmax_k(s), v = a^T x + (sum a)·C
// x: [64,784,512] f32, W/C: [512,32] f32, out: [64, 512*32] f32
#define NB 64
#define HW 784
#define DD 512
#define KK 32
#define BPB 14            // blocks per batch
#define PPB 56            // pixels per block
#define CHUNK 32
#define NCHUNK 2
#define XROW 516          // fp32 row stride: 516%32=4 -> banks rotate 4/row; 16B-aligned rows

typedef __attribute__((ext_vector_type(8))) short bf16x8;   // 8 bf16 (4 VGPR)
typedef __attribute__((ext_vector_type(4))) float f32x4;    // MFMA 16x16 acc

// ws: partials [NB*BPB][8 waves][8 frags][64 lanes] float4, then asums [NB*BPB][KK]
#define PART_F   ((size_t)NB * BPB * 8 * 8 * 64 * 4)
#define ASUM_OFF PART_F
#define WS_NEED  ((PART_F + (size_t)NB * BPB * KK) * sizeof(float))

__device__ __forceinline__ unsigned short f2bf(float f) {
    unsigned u = __float_as_uint(f);
    u += 0x7fffu + ((u >> 16) & 1u);      // round-to-nearest-even
    return (unsigned short)(u >> 16);
}
__device__ __forceinline__ float bf2f(unsigned short u) {
    return __uint_as_float((unsigned)u << 16);
}
__device__ __forceinline__ bf16x8 cvt8v(float4 a, float4 b) {
    bf16x8 r;
    r[0] = (short)f2bf(a.x); r[1] = (short)f2bf(a.y);
    r[2] = (short)f2bf(a.z); r[3] = (short)f2bf(a.w);
    r[4] = (short)f2bf(b.x); r[5] = (short)f2bf(b.y);
    r[6] = (short)f2bf(b.z); r[7] = (short)f2bf(b.w);
    return r;
}
__device__ __forceinline__ void gload16(const float4* g, float4* l) {
    __builtin_amdgcn_global_load_lds(
        (const __attribute__((address_space(1))) unsigned int*)g,
        (__attribute__((address_space(3))) unsigned int*)l,
        16, 0, 0);
}

template <bool USE_WS>
__global__ __launch_bounds__(512) void netvlad_stage1(
    const float* __restrict__ x, const float* __restrict__ Wg,
    const float* __restrict__ Cg, float* __restrict__ out,
    float* __restrict__ ws)
{
    // LDS ~75.6 KB -> 2 blocks/CU (16 waves/CU)
    __shared__ __align__(16) float xs[CHUNK * XROW];           // 66.0 KB fp32 chunk
    __shared__ unsigned short spart[4][CHUNK][34];             // 8.7 KB bf16 d-split partials
    __shared__ __align__(16) unsigned short aTe[KK * 40];      // a^T [k][px] (2.56 KB)
    __shared__ float asumF[KK];

    const int tid = threadIdx.x;
    const int l   = tid & 63, w = tid >> 6;      // lane, wave 0..7
    const int l15 = l & 15,  lq = l >> 4;        // frag row/col, quarter
    const int d4  = w & 3;                        // phase-A d-slice 128*d4
    const int pgrp= w >> 2;                       // phase-A px-group (16 px)
    const int k   = tid & 31, pg = tid >> 5;     // softmax mapping: pg 0..15
    const int bid = blockIdx.x;
    const int b   = bid / BPB;
    const int pb  = (bid % BPB) * PPB;
    const float* xb = x + (size_t)b * HW * DD;

    // W B-frags: Wf[ks][nt] lane holds W[d = d4*128+ks*32+lq*8+j][nt*16+l15]
    bf16x8 Wf[4][2];
#pragma unroll
    for (int ks = 0; ks < 4; ++ks)
#pragma unroll
        for (int nt = 0; nt < 2; ++nt)
#pragma unroll
            for (int j = 0; j < 8; ++j)
                Wf[ks][nt][j] = (short)f2bf(Wg[(d4*128 + ks*32 + lq*8 + j) * KK + nt*16 + l15]);

    // phase-C: wave owns d-slice [64w, 64w+64): acc[mt][nt] -> k=mt*16+lq*4+jj, d=64w+nt*16+l15
    f32x4 acc[2][4];
#pragma unroll
    for (int mt = 0; mt < 2; ++mt)
#pragma unroll
        for (int nt = 0; nt < 4; ++nt)
#pragma unroll
            for (int jj = 0; jj < 4; ++jj) acc[mt][nt][jj] = 0.f;
    float asum_part = 0.f;

    // Pure-DMA staging: 64 1KB spans (32 rows x 2 halves), 8 per wave.
    // dst is wave-uniform (HW adds lane*16); src is per-lane. Row pad (516)
    // is outside every span, so each span is contiguous as required.
    auto stageIssue = [&](int c) {
#pragma unroll
        for (int j = 0; j < 8; ++j) {
            const int idx = w*8 + j;            // uniform within wave
            const int r = idx >> 1, h = idx & 1;
            const int p = c*CHUNK + r;
            const int gp = pb + (p < PPB ? p : PPB - 1);   // clamp pad rows
            gload16((const float4*)(xb + (size_t)gp * DD + h*256) + l,
                    (float4*)&xs[r*XROW + h*256]);
        }
    };

    stageIssue(0);
    __syncthreads();        // barrier drains vmcnt -> chunk 0 ready

    for (int c = 0; c < NCHUNK; ++c) {
        // ---- phase A: s[16px(pgrp)][32k] partial over d-slice 128*d4 ----
        f32x4 sp[2];
#pragma unroll
        for (int nt = 0; nt < 2; ++nt)
#pragma unroll
            for (int jj = 0; jj < 4; ++jj) sp[nt][jj] = 0.f;
#pragma unroll
        for (int ks = 0; ks < 4; ++ks) {
            const float* pa = &xs[(pgrp*16 + l15)*XROW + d4*128 + ks*32 + lq*8];
            const bf16x8 af = cvt8v(*(const float4*)pa, *(const float4*)(pa + 4));
#pragma unroll
            for (int nt = 0; nt < 2; ++nt)
                sp[nt] = __builtin_amdgcn_mfma_f32_16x16x32_bf16(
                    af, Wf[ks][nt], sp[nt], 0, 0, 0);
        }
#pragma unroll
        for (int nt = 0; nt < 2; ++nt)
#pragma unroll
            for (int jj = 0; jj < 4; ++jj)
                spart[d4][pgrp*16 + lq*4 + jj][nt*16 + l15] = f2bf(sp[nt][jj]);
        __syncthreads();

        // ---- phase B: softmax over k; thread (pg,k), px = pg + 16i ----
        const int valid = (PPB - c*CHUNK < CHUNK) ? (PPB - c*CHUNK) : CHUNK;
#pragma unroll
        for (int i = 0; i < 2; ++i) {
            const int p = pg + 16*i;
            const float s = bf2f(spart[0][p][k]) + bf2f(spart[1][p][k])
                          + bf2f(spart[2][p][k]) + bf2f(spart[3][p][k]);
            const float e = __expf(s);
            float su = e;
#pragma unroll
            for (int msk = 16; msk >= 1; msk >>= 1)
                su += __shfl_xor(su, msk);
            const float a = (p < valid) ? e * __builtin_amdgcn_rcpf(su) : 0.f;
            asum_part += a;
            aTe[k*40 + p] = f2bf(a);
        }
        __syncthreads();

        // ---- phase C: v^T[32k][64d-slice] += a^T[32k][32px] · x[32px][d] ----
        bf16x8 afr[2];
#pragma unroll
        for (int mt = 0; mt < 2; ++mt)
            afr[mt] = *(const bf16x8*)&aTe[(mt*16 + l15)*40 + lq*8];
#pragma unroll
        for (int nt = 0; nt < 4; ++nt) {
            const int d = w*64 + nt*16 + l15;
            bf16x8 bfr;
#pragma unroll
            for (int j = 0; j < 8; ++j) {                  // column read of x, j rotated
                const int jj = (j + 2*lq) & 7;             // per-quarter bank stagger
                bfr[jj] = (short)f2bf(xs[(lq*8 + jj)*XROW + d]);
            }
#pragma unroll
            for (int mt = 0; mt < 2; ++mt)
                acc[mt][nt] = __builtin_amdgcn_mfma_f32_16x16x32_bf16(
                    afr[mt], bfr, acc[mt][nt], 0, 0, 0);
        }
        __syncthreads();

        if (c + 1 < NCHUNK) {       // xs free after phase C's barrier
            stageIssue(c + 1);
            __syncthreads();        // drain: next chunk ready
        }
    }

    // ---- block asum[k] reduce (ared aliases aTe: dead after last phase C) ----
    float* ared = (float*)aTe;     // [16][32]
    ared[pg*KK + k] = asum_part;
    __syncthreads();
    if (tid < KK) {
        float s = 0.f;
#pragma unroll
        for (int g = 0; g < 16; ++g) s += ared[g*KK + tid];
        if (USE_WS) ws[ASUM_OFF + (size_t)bid * KK + tid] = s;
        else        asumF[tid] = s;
    }

    if (USE_WS) {
        // partial store, thread-major: fully coalesced float4 streaming
        float4* o = (float4*)ws + ((size_t)bid * 8 + w) * (8 * 64);
#pragma unroll
        for (int mt = 0; mt < 2; ++mt)
#pragma unroll
            for (int nt = 0; nt < 4; ++nt)
                o[(mt*4 + nt)*64 + l] = make_float4(acc[mt][nt][0], acc[mt][nt][1],
                                                    acc[mt][nt][2], acc[mt][nt][3]);
    } else {
        __syncthreads();
        float* ob = out + (size_t)b * (DD * KK);
#pragma unroll
        for (int mt = 0; mt < 2; ++mt)
#pragma unroll
            for (int nt = 0; nt < 4; ++nt)
#pragma unroll
                for (int jj = 0; jj < 4; ++jj) {
                    const int kk = mt*16 + lq*4 + jj;
                    const int d  = w*64 + nt*16 + l15;
                    atomicAdd(&ob[d*KK + kk], acc[mt][nt][jj] + asumF[kk] * Cg[d*KK + kk]);
                }
    }
}

// Stage 2: block = (b, 128-d slice): sum 14 partials, add asum_total*C, write canonical
__global__ __launch_bounds__(256) void netvlad_stage2(
    const float* __restrict__ ws, const float* __restrict__ Cg,
    float* __restrict__ out)
{
    __shared__ float lds[128 * 33];    // canonical [d_local][k], padded
    __shared__ float asumT[KK];

    const int t = threadIdx.x;
    const int b = blockIdx.x >> 2;
    const int jsl = blockIdx.x & 3;    // d-slice [128*jsl, +128) = stage1 waves {2jsl, 2jsl+1}

    if (t < KK) {
        float s = 0.f;
#pragma unroll
        for (int p = 0; p < BPB; ++p)
            s += ws[ASUM_OFF + (size_t)(b*BPB + p) * KK + t];
        asumT[t] = s;
    }

    const float4* wsp = (const float4*)ws;
    float4 v[4];
#pragma unroll
    for (int i = 0; i < 4; ++i) v[i] = make_float4(0.f, 0.f, 0.f, 0.f);
    for (int p = 0; p < BPB; ++p) {
        const size_t base = (size_t)(b*BPB + p) * 8 * (8 * 64);
#pragma unroll
        for (int i = 0; i < 4; ++i) {
            const int flat = t + 256*i;           // (w2, fr, lane)
            const int g = flat >> 6, lane = flat & 63;
            const int w2 = g >> 3, fr = g & 7;
            const float4 f4 = wsp[base + ((size_t)(2*jsl + w2) * 8 + fr)*64 + lane];
            v[i].x += f4.x; v[i].y += f4.y; v[i].z += f4.z; v[i].w += f4.w;
        }
    }
    // scatter frag layout -> canonical [d_local][k]
#pragma unroll
    for (int i = 0; i < 4; ++i) {
        const int flat = t + 256*i;
        const int g = flat >> 6, lane = flat & 63;
        const int w2 = g >> 3, fr = g & 7;
        const int mt = fr >> 2, nt = fr & 3;
        const int q = lane >> 4, r15 = lane & 15;
        const int dl = w2*64 + nt*16 + r15;
        const int kb = mt*16 + q*4;
        lds[dl*33 + kb + 0] = v[i].x;
        lds[dl*33 + kb + 1] = v[i].y;
        lds[dl*33 + kb + 2] = v[i].z;
        lds[dl*33 + kb + 3] = v[i].w;
    }
    __syncthreads();

    float* outw = out + (size_t)b * (DD*KK) + jsl * 128 * KK;
    const float* Cw = Cg + jsl * 128 * KK;
#pragma unroll
    for (int i = 0; i < 4; ++i) {
        const int o4 = t + 256*i;
        const int dl = o4 >> 3, kq = (o4 & 7) * 4;
        const float4 c4 = *(const float4*)&Cw[dl*KK + kq];
        float4 rr;
        rr.x = lds[dl*33 + kq + 0] + asumT[kq + 0] * c4.x;
        rr.y = lds[dl*33 + kq + 1] + asumT[kq + 1] * c4.y;
        rr.z = lds[dl*33 + kq + 2] + asumT[kq + 2] * c4.z;
        rr.w = lds[dl*33 + kq + 3] + asumT[kq + 3] * c4.w;
        ((float4*)outw)[o4] = rr;
    }
}

extern "C" void kernel_launch(void* const* d_in, const int* in_sizes, int n_in,
                              void* d_out, int out_size, void* d_ws, size_t ws_size,
                              hipStream_t stream) {
    const float* x = (const float*)d_in[0];
    const float* W = (const float*)d_in[1];
    const float* C = (const float*)d_in[2];
    float* out = (float*)d_out;

    if (ws_size >= WS_NEED) {
        float* ws = (float*)d_ws;
        netvlad_stage1<true><<<dim3(NB * BPB), dim3(512), 0, stream>>>(x, W, C, out, ws);
        netvlad_stage2<<<dim3(NB * 4), dim3(256), 0, stream>>>(ws, C, out);
    } else {
        hipMemsetAsync(out, 0, (size_t)out_size * sizeof(float), stream);
        netvlad_stage1<false><<<dim3(NB * BPB), dim3(512), 0, stream>>>(x, W, C, out, nullptr);
    }
}

// Round 11
// 50.502 us; speedup vs baseline: 1.2492x; 1.1726x over previous
//
#include <hip/hip_runtime.h>

// NetVLAD fused via bf16 MFMA, two-stage, single-chunk blocks (5 barriers).
//   s = x·W, a = softmax_k(s), v = a^T x + (sum a)·C
// x: [64,784,512] f32, W/C: [512,32] f32, out: [64, 512*32] f32
#define NB 64
#define HW 784
#define DD 512
#define KK 32
#define BPB 28            // blocks per batch (28 px each: 28*28 = 784 = HW)
#define PPB 28            // valid pixels per block
#define SLOTS 32          // px slots (28 valid + 4 clamped, a=0)

typedef __attribute__((ext_vector_type(8))) short bf16x8;   // 8 bf16 (4 VGPR)
typedef __attribute__((ext_vector_type(4))) float f32x4;    // MFMA 16x16 acc
typedef __attribute__((ext_vector_type(4))) unsigned short u16x4;

// ws: bf16 partials [NB*BPB][4 waves][16 frags][64 lanes] u16x4 (8 B each),
//     then fp32 asums [NB*BPB][KK]
#define NBLK (NB * BPB)
#define PART_BYTES ((size_t)NBLK * 4 * 16 * 64 * 8)
#define WS_NEED    (PART_BYTES + (size_t)NBLK * KK * 4)

__device__ __forceinline__ unsigned short f2bf(float f) {
    unsigned u = __float_as_uint(f);
    u += 0x7fffu + ((u >> 16) & 1u);      // round-to-nearest-even
    return (unsigned short)(u >> 16);
}
__device__ __forceinline__ float bf2f(unsigned short u) {
    return __uint_as_float((unsigned)u << 16);
}

template <bool USE_WS>
__global__ __launch_bounds__(256) void netvlad_stage1(
    const float* __restrict__ x, const float* __restrict__ Wg,
    const float* __restrict__ Cg, float* __restrict__ out,
    void* __restrict__ ws)
{
    // LDS ~44.4 KB -> 3 blocks/CU if VGPR <= 128
    __shared__ __align__(16) unsigned short xs[SLOTS * 520];   // 33.3 KB bf16
    __shared__ unsigned short spart[4][SLOTS][33];             // 8.4 KB bf16 d-split partials
    __shared__ __align__(16) unsigned short aTe[KK * 40];      // a^T [k][px] 2.5 KB
    __shared__ float asumF[KK];

    const int tid = threadIdx.x;
    const int l   = tid & 63, w = tid >> 6;      // lane, wave 0..3 (= d-slice 128w)
    const int l15 = l & 15,  lq = l >> 4;        // frag row/col, quarter
    const int k   = tid & 31, pg = tid >> 5;     // softmax mapping: pg 0..7
    const int bid = blockIdx.x;
    const int b   = bid / BPB;
    const int pb  = (bid % BPB) * PPB;
    const float* xb = x + (size_t)b * HW * DD;

    // W B-frags: Wf[ks][nt] lane holds W[d = w*128+ks*32+lq*8+j][nt*16+l15]
    bf16x8 Wf[4][2];
#pragma unroll
    for (int ks = 0; ks < 4; ++ks)
#pragma unroll
        for (int nt = 0; nt < 2; ++nt)
#pragma unroll
            for (int j = 0; j < 8; ++j)
                Wf[ks][nt][j] = (short)f2bf(Wg[(w*128 + ks*32 + lq*8 + j) * KK + nt*16 + l15]);

    // phase-C acc: k = mt*16+lq*4+jj, d = w*128 + nt*16 + l15
    f32x4 acc[2][8];
#pragma unroll
    for (int mt = 0; mt < 2; ++mt)
#pragma unroll
        for (int nt = 0; nt < 8; ++nt)
#pragma unroll
            for (int jj = 0; jj < 4; ++jj) acc[mt][nt][jj] = 0.f;
    float asum_part = 0.f;

    // ---- stage: 32 px * 512 f32 -> bf16 LDS; 16 float4/thread in 2 batches ----
#pragma unroll
    for (int h = 0; h < 2; ++h) {
        float4 r[8];
#pragma unroll
        for (int j = 0; j < 8; ++j) {
            const int f = tid + 256*(h*8 + j), row = f >> 7, c4 = f & 127;
            const int gp = pb + (row < PPB ? row : PPB - 1);   // clamp pad rows
            r[j] = *(const float4*)(xb + (size_t)gp * DD + c4*4);
        }
#pragma unroll
        for (int j = 0; j < 8; ++j) {
            const int f = tid + 256*(h*8 + j), row = f >> 7, c4 = f & 127;
            uint2 pk = make_uint2((unsigned)f2bf(r[j].x) | ((unsigned)f2bf(r[j].y) << 16),
                                  (unsigned)f2bf(r[j].z) | ((unsigned)f2bf(r[j].w) << 16));
            *(uint2*)&xs[row*520 + c4*4] = pk;
        }
    }
    __syncthreads();

    // ---- phase A: s[32px][32k] partial over this wave's 128-d slice (16 MFMA) ----
    {
        f32x4 sp[2][2];
#pragma unroll
        for (int mt = 0; mt < 2; ++mt)
#pragma unroll
            for (int nt = 0; nt < 2; ++nt)
#pragma unroll
                for (int jj = 0; jj < 4; ++jj) sp[mt][nt][jj] = 0.f;
#pragma unroll
        for (int ks = 0; ks < 4; ++ks) {
            bf16x8 af[2];
#pragma unroll
            for (int mt = 0; mt < 2; ++mt)
                af[mt] = *(const bf16x8*)&xs[(mt*16 + l15)*520 + w*128 + ks*32 + lq*8];
#pragma unroll
            for (int mt = 0; mt < 2; ++mt)
#pragma unroll
                for (int nt = 0; nt < 2; ++nt)
                    sp[mt][nt] = __builtin_amdgcn_mfma_f32_16x16x32_bf16(
                        af[mt], Wf[ks][nt], sp[mt][nt], 0, 0, 0);
        }
#pragma unroll
        for (int mt = 0; mt < 2; ++mt)
#pragma unroll
            for (int nt = 0; nt < 2; ++nt)
#pragma unroll
                for (int jj = 0; jj < 4; ++jj)
                    spart[w][mt*16 + lq*4 + jj][nt*16 + l15] = f2bf(sp[mt][nt][jj]);
    }
    __syncthreads();

    // ---- phase B: softmax over k; thread (pg,k), px = pg + 8i ----
#pragma unroll
    for (int i = 0; i < 4; ++i) {
        const int p = pg + 8*i;
        const float s = bf2f(spart[0][p][k]) + bf2f(spart[1][p][k])
                      + bf2f(spart[2][p][k]) + bf2f(spart[3][p][k]);
        const float e = __expf(s);
        float su = e;
#pragma unroll
        for (int msk = 16; msk >= 1; msk >>= 1)
            su += __shfl_xor(su, msk);
        const float a = (p < PPB) ? e * __builtin_amdgcn_rcpf(su) : 0.f;
        asum_part += a;
        aTe[k*40 + p] = f2bf(a);
    }
    __syncthreads();

    // ---- phase C: v^T[32k][128d-slice] += a^T[32k][32px] · x[32px][d] (16 MFMA) ----
    {
        bf16x8 afr[2];
#pragma unroll
        for (int mt = 0; mt < 2; ++mt)
            afr[mt] = *(const bf16x8*)&aTe[(mt*16 + l15)*40 + lq*8];
#pragma unroll
        for (int nt = 0; nt < 8; ++nt) {
            const int d = w*128 + nt*16 + l15;
            bf16x8 bfr;
#pragma unroll
            for (int j = 0; j < 8; ++j) {                  // column read of x, j rotated
                const int jj = (j + 2*lq) & 7;             // per-quarter bank stagger
                bfr[jj] = (short)xs[(lq*8 + jj)*520 + d];
            }
#pragma unroll
            for (int mt = 0; mt < 2; ++mt)
                acc[mt][nt] = __builtin_amdgcn_mfma_f32_16x16x32_bf16(
                    afr[mt], bfr, acc[mt][nt], 0, 0, 0);
        }
    }
    __syncthreads();

    // ---- block asum[k] reduce (ared aliases aTe: dead after phase C) ----
    float* ared = (float*)aTe;     // [8][32]
    ared[pg*KK + k] = asum_part;
    __syncthreads();
    float* wsA = (float*)((char*)ws + PART_BYTES);
    if (tid < KK) {
        float s = 0.f;
#pragma unroll
        for (int g = 0; g < 8; ++g) s += ared[g*KK + tid];
        if (USE_WS) wsA[(size_t)bid * KK + tid] = s;
        else        asumF[tid] = s;
    }

    if (USE_WS) {
        // bf16 partial store, thread-major: coalesced ushort4 streaming
        u16x4* o = (u16x4*)ws + ((size_t)bid * 4 + w) * (16 * 64);
#pragma unroll
        for (int mt = 0; mt < 2; ++mt)
#pragma unroll
            for (int nt = 0; nt < 8; ++nt) {
                u16x4 u;
                u[0] = f2bf(acc[mt][nt][0]); u[1] = f2bf(acc[mt][nt][1]);
                u[2] = f2bf(acc[mt][nt][2]); u[3] = f2bf(acc[mt][nt][3]);
                o[(mt*8 + nt)*64 + l] = u;
            }
    } else {
        __syncthreads();
        float* ob = out + (size_t)b * (DD * KK);
#pragma unroll
        for (int mt = 0; mt < 2; ++mt)
#pragma unroll
            for (int nt = 0; nt < 8; ++nt)
#pragma unroll
                for (int jj = 0; jj < 4; ++jj) {
                    const int kk = mt*16 + lq*4 + jj;
                    const int d  = w*128 + nt*16 + l15;
                    atomicAdd(&ob[d*KK + kk], acc[mt][nt][jj] + asumF[kk] * Cg[d*KK + kk]);
                }
    }
}

// Stage 2: block = (b, 128-d slice jsl): sum 28 bf16 partials, add asum*C, write
__global__ __launch_bounds__(256) void netvlad_stage2(
    const void* __restrict__ ws, const float* __restrict__ Cg,
    float* __restrict__ out)
{
    __shared__ float lds[128 * 33];    // canonical [d_local][k], padded
    __shared__ float asumT[KK];

    const int t = threadIdx.x;
    const int b = blockIdx.x >> 2;
    const int jsl = blockIdx.x & 3;    // = stage1 wave index (d-slice 128*jsl)

    const float* wsA = (const float*)((const char*)ws + PART_BYTES);
    if (t < KK) {
        float s = 0.f;
#pragma unroll
        for (int p = 0; p < BPB; ++p)
            s += wsA[(size_t)(b*BPB + p) * KK + t];
        asumT[t] = s;
    }

    const u16x4* wsp = (const u16x4*)ws;
    float4 v[4];
#pragma unroll
    for (int i = 0; i < 4; ++i) v[i] = make_float4(0.f, 0.f, 0.f, 0.f);
    for (int p = 0; p < BPB; ++p) {
        const size_t base = ((size_t)(b*BPB + p) * 4 + jsl) * (16 * 64);
#pragma unroll
        for (int i = 0; i < 4; ++i) {
            const u16x4 u = wsp[base + t + 256*i];
            v[i].x += bf2f(u[0]); v[i].y += bf2f(u[1]);
            v[i].z += bf2f(u[2]); v[i].w += bf2f(u[3]);
        }
    }
    // scatter frag layout -> canonical [d_local][k]
#pragma unroll
    for (int i = 0; i < 4; ++i) {
        const int flat = t + 256*i;               // fr*64 + lane
        const int fr = flat >> 6, lane = flat & 63;
        const int mt = fr >> 3, nt = fr & 7;
        const int q = lane >> 4, r15 = lane & 15;
        const int dl = nt*16 + r15;
        const int kb = mt*16 + q*4;
        lds[dl*33 + kb + 0] = v[i].x;
        lds[dl*33 + kb + 1] = v[i].y;
        lds[dl*33 + kb + 2] = v[i].z;
        lds[dl*33 + kb + 3] = v[i].w;
    }
    __syncthreads();

    float* outw = out + (size_t)b * (DD*KK) + jsl * 128 * KK;
    const float* Cw = Cg + jsl * 128 * KK;
#pragma unroll
    for (int i = 0; i < 4; ++i) {
        const int o4 = t + 256*i;
        const int dl = o4 >> 3, kq = (o4 & 7) * 4;
        const float4 c4 = *(const float4*)&Cw[dl*KK + kq];
        float4 rr;
        rr.x = lds[dl*33 + kq + 0] + asumT[kq + 0] * c4.x;
        rr.y = lds[dl*33 + kq + 1] + asumT[kq + 1] * c4.y;
        rr.z = lds[dl*33 + kq + 2] + asumT[kq + 2] * c4.z;
        rr.w = lds[dl*33 + kq + 3] + asumT[kq + 3] * c4.w;
        ((float4*)outw)[o4] = rr;
    }
}

extern "C" void kernel_launch(void* const* d_in, const int* in_sizes, int n_in,
                              void* d_out, int out_size, void* d_ws, size_t ws_size,
                              hipStream_t stream) {
    const float* x = (const float*)d_in[0];
    const float* W = (const float*)d_in[1];
    const float* C = (const float*)d_in[2];
    float* out = (float*)d_out;

    if (ws_size >= WS_NEED) {
        netvlad_stage1<true><<<dim3(NBLK), dim3(256), 0, stream>>>(x, W, C, out, d_ws);
        netvlad_stage2<<<dim3(NB * 4), dim3(256), 0, stream>>>(d_ws, C, out);
    } else {
        hipMemsetAsync(out, 0, (size_t)out_size * sizeof(float), stream);
        netvlad_stage1<false><<<dim3(NBLK), dim3(256), 0, stream>>>(x, W, C, out, d_ws);
    }
}

// Round 13
// 49.011 us; speedup vs baseline: 1.2872x; 1.0304x over previous
//
#include <hip/hip_runtime.h>

// NetVLAD fused via bf16 MFMA, two-stage, single-chunk blocks (5 barriers).
// R13 = R11 structure (proven) + VALU diet: cvt_pk packing in staging/epilogue,
// fp32 spart (no bf16 round-trip). Layouts identical to R11.
//   s = x·W, a = softmax_k(s), v = a^T x + (sum a)·C
// x: [64,784,512] f32, W/C: [512,32] f32, out: [64, 512*32] f32
#define NB 64
#define HW 784
#define DD 512
#define KK 32
#define BPB 28            // blocks per batch (28 px each: 28*28 = 784 = HW)
#define PPB 28            // valid pixels per block
#define SLOTS 32          // px slots (28 valid + 4 clamped, a=0)

typedef __attribute__((ext_vector_type(8))) short bf16x8;   // 8 bf16 (4 VGPR)
typedef __attribute__((ext_vector_type(4))) float f32x4;    // MFMA 16x16 acc
typedef __attribute__((ext_vector_type(4))) unsigned short u16x4;

// ws: bf16 partials [NB*BPB][4 waves][16 frags][64 lanes] u16x4 (8 B each),
//     then fp32 asums [NB*BPB][KK]
#define NBLK (NB * BPB)
#define PART_BYTES ((size_t)NBLK * 4 * 16 * 64 * 8)
#define WS_NEED    (PART_BYTES + (size_t)NBLK * KK * 4)

__device__ __forceinline__ unsigned short f2bf(float f) {
    unsigned u = __float_as_uint(f);
    u += 0x7fffu + ((u >> 16) & 1u);      // round-to-nearest-even
    return (unsigned short)(u >> 16);
}
__device__ __forceinline__ float bf2f(unsigned short u) {
    return __uint_as_float((unsigned)u << 16);
}
// packed f32x2 -> bf16x2, one instruction (lo = a, hi = b; T12 recipe, HW-verified)
__device__ __forceinline__ unsigned cvtpk(float a, float b) {
    unsigned r;
    asm("v_cvt_pk_bf16_f32 %0, %1, %2" : "=v"(r) : "v"(a), "v"(b));
    return r;
}

template <bool USE_WS>
__global__ __launch_bounds__(256) void netvlad_stage1(
    const float* __restrict__ x, const float* __restrict__ Wg,
    const float* __restrict__ Cg, float* __restrict__ out,
    void* __restrict__ ws)
{
    // LDS ~52.9 KB -> 3 blocks/CU (3*53,248 = 159.7 KB <= 160 KB)
    __shared__ __align__(16) unsigned short xs[SLOTS * 520];   // 33.3 KB bf16
    __shared__ float spart[4][SLOTS][33];                      // 16.9 KB fp32 d-split partials
    __shared__ __align__(16) unsigned short aTe[KK * 40];      // a^T [k][px] 2.5 KB
    __shared__ float asumF[KK];

    const int tid = threadIdx.x;
    const int l   = tid & 63, w = tid >> 6;      // lane, wave 0..3 (= d-slice 128w)
    const int l15 = l & 15,  lq = l >> 4;        // frag row/col, quarter
    const int k   = tid & 31, pg = tid >> 5;     // softmax mapping: pg 0..7
    const int bid = blockIdx.x;
    const int b   = bid / BPB;
    const int pb  = (bid % BPB) * PPB;
    const float* xb = x + (size_t)b * HW * DD;

    // W B-frags: Wf[ks][nt] lane holds W[d = w*128+ks*32+lq*8+j][nt*16+l15]
    bf16x8 Wf[4][2];
#pragma unroll
    for (int ks = 0; ks < 4; ++ks)
#pragma unroll
        for (int nt = 0; nt < 2; ++nt)
#pragma unroll
            for (int j = 0; j < 8; ++j)
                Wf[ks][nt][j] = (short)f2bf(Wg[(w*128 + ks*32 + lq*8 + j) * KK + nt*16 + l15]);

    // phase-C acc: k = mt*16+lq*4+jj, d = w*128 + nt*16 + l15
    f32x4 acc[2][8];
#pragma unroll
    for (int mt = 0; mt < 2; ++mt)
#pragma unroll
        for (int nt = 0; nt < 8; ++nt)
#pragma unroll
            for (int jj = 0; jj < 4; ++jj) acc[mt][nt][jj] = 0.f;
    float asum_part = 0.f;

    // ---- stage: 32 px * 512 f32 -> bf16 LDS; 16 float4/thread in 2 batches ----
#pragma unroll
    for (int h = 0; h < 2; ++h) {
        float4 r[8];
#pragma unroll
        for (int j = 0; j < 8; ++j) {
            const int f = tid + 256*(h*8 + j), row = f >> 7, c4 = f & 127;
            const int gp = pb + (row < PPB ? row : PPB - 1);   // clamp pad rows
            r[j] = *(const float4*)(xb + (size_t)gp * DD + c4*4);
        }
#pragma unroll
        for (int j = 0; j < 8; ++j) {
            const int f = tid + 256*(h*8 + j), row = f >> 7, c4 = f & 127;
            uint2 pk = make_uint2(cvtpk(r[j].x, r[j].y), cvtpk(r[j].z, r[j].w));
            *(uint2*)&xs[row*520 + c4*4] = pk;
        }
    }
    __syncthreads();

    // ---- phase A: s[32px][32k] partial over this wave's 128-d slice (16 MFMA) ----
    {
        f32x4 sp[2][2];
#pragma unroll
        for (int mt = 0; mt < 2; ++mt)
#pragma unroll
            for (int nt = 0; nt < 2; ++nt)
#pragma unroll
                for (int jj = 0; jj < 4; ++jj) sp[mt][nt][jj] = 0.f;
#pragma unroll
        for (int ks = 0; ks < 4; ++ks) {
            bf16x8 af[2];
#pragma unroll
            for (int mt = 0; mt < 2; ++mt)
                af[mt] = *(const bf16x8*)&xs[(mt*16 + l15)*520 + w*128 + ks*32 + lq*8];
#pragma unroll
            for (int mt = 0; mt < 2; ++mt)
#pragma unroll
                for (int nt = 0; nt < 2; ++nt)
                    sp[mt][nt] = __builtin_amdgcn_mfma_f32_16x16x32_bf16(
                        af[mt], Wf[ks][nt], sp[mt][nt], 0, 0, 0);
        }
#pragma unroll
        for (int mt = 0; mt < 2; ++mt)
#pragma unroll
            for (int nt = 0; nt < 2; ++nt)
#pragma unroll
                for (int jj = 0; jj < 4; ++jj)
                    spart[w][mt*16 + lq*4 + jj][nt*16 + l15] = sp[mt][nt][jj];
    }
    __syncthreads();

    // ---- phase B: softmax over k; thread (pg,k), px = pg + 8i ----
#pragma unroll
    for (int i = 0; i < 4; ++i) {
        const int p = pg + 8*i;
        const float s = spart[0][p][k] + spart[1][p][k]
                      + spart[2][p][k] + spart[3][p][k];
        const float e = __expf(s);
        float su = e;
#pragma unroll
        for (int msk = 16; msk >= 1; msk >>= 1)
            su += __shfl_xor(su, msk);
        const float a = (p < PPB) ? e * __builtin_amdgcn_rcpf(su) : 0.f;
        asum_part += a;
        aTe[k*40 + p] = f2bf(a);
    }
    __syncthreads();

    // ---- phase C: v^T[32k][128d-slice] += a^T[32k][32px] · x[32px][d] (16 MFMA) ----
    {
        bf16x8 afr[2];
#pragma unroll
        for (int mt = 0; mt < 2; ++mt)
            afr[mt] = *(const bf16x8*)&aTe[(mt*16 + l15)*40 + lq*8];
#pragma unroll
        for (int nt = 0; nt < 8; ++nt) {
            const int d = w*128 + nt*16 + l15;
            bf16x8 bfr;
#pragma unroll
            for (int j = 0; j < 8; ++j) {                  // column read of x, j rotated
                const int jj = (j + 2*lq) & 7;             // per-quarter bank stagger
                bfr[jj] = (short)xs[(lq*8 + jj)*520 + d];
            }
#pragma unroll
            for (int mt = 0; mt < 2; ++mt)
                acc[mt][nt] = __builtin_amdgcn_mfma_f32_16x16x32_bf16(
                    afr[mt], bfr, acc[mt][nt], 0, 0, 0);
        }
    }
    __syncthreads();

    // ---- block asum[k] reduce (ared aliases aTe: dead after phase C) ----
    float* ared = (float*)aTe;     // [8][32]
    ared[pg*KK + k] = asum_part;
    __syncthreads();
    float* wsA = (float*)((char*)ws + PART_BYTES);
    if (tid < KK) {
        float s = 0.f;
#pragma unroll
        for (int g = 0; g < 8; ++g) s += ared[g*KK + tid];
        if (USE_WS) wsA[(size_t)bid * KK + tid] = s;
        else        asumF[tid] = s;
    }

    if (USE_WS) {
        // bf16 partial store, thread-major: coalesced 8B streaming (cvt_pk packed)
        u16x4* o = (u16x4*)ws + ((size_t)bid * 4 + w) * (16 * 64);
#pragma unroll
        for (int mt = 0; mt < 2; ++mt)
#pragma unroll
            for (int nt = 0; nt < 8; ++nt) {
                uint2 pk = make_uint2(cvtpk(acc[mt][nt][0], acc[mt][nt][1]),
                                      cvtpk(acc[mt][nt][2], acc[mt][nt][3]));
                *(uint2*)&o[(mt*8 + nt)*64 + l] = pk;
            }
    } else {
        __syncthreads();
        float* ob = out + (size_t)b * (DD * KK);
#pragma unroll
        for (int mt = 0; mt < 2; ++mt)
#pragma unroll
            for (int nt = 0; nt < 8; ++nt)
#pragma unroll
                for (int jj = 0; jj < 4; ++jj) {
                    const int kk = mt*16 + lq*4 + jj;
                    const int d  = w*128 + nt*16 + l15;
                    atomicAdd(&ob[d*KK + kk], acc[mt][nt][jj] + asumF[kk] * Cg[d*KK + kk]);
                }
    }
}

// Stage 2: block = (b, 128-d slice jsl): sum 28 bf16 partials, add asum*C, write
__global__ __launch_bounds__(256) void netvlad_stage2(
    const void* __restrict__ ws, const float* __restrict__ Cg,
    float* __restrict__ out)
{
    __shared__ float lds[128 * 33];    // canonical [d_local][k], padded
    __shared__ float asumT[KK];

    const int t = threadIdx.x;
    const int b = blockIdx.x >> 2;
    const int jsl = blockIdx.x & 3;    // = stage1 wave index (d-slice 128*jsl)

    const float* wsA = (const float*)((const char*)ws + PART_BYTES);
    if (t < KK) {
        float s = 0.f;
#pragma unroll
        for (int p = 0; p < BPB; ++p)
            s += wsA[(size_t)(b*BPB + p) * KK + t];
        asumT[t] = s;
    }

    const u16x4* wsp = (const u16x4*)ws;
    float4 v[4];
#pragma unroll
    for (int i = 0; i < 4; ++i) v[i] = make_float4(0.f, 0.f, 0.f, 0.f);
    for (int p = 0; p < BPB; ++p) {
        const size_t base = ((size_t)(b*BPB + p) * 4 + jsl) * (16 * 64);
#pragma unroll
        for (int i = 0; i < 4; ++i) {
            const u16x4 u = wsp[base + t + 256*i];
            v[i].x += bf2f(u[0]); v[i].y += bf2f(u[1]);
            v[i].z += bf2f(u[2]); v[i].w += bf2f(u[3]);
        }
    }
    // scatter frag layout -> canonical [d_local][k]
#pragma unroll
    for (int i = 0; i < 4; ++i) {
        const int flat = t + 256*i;               // fr*64 + lane
        const int fr = flat >> 6, lane = flat & 63;
        const int mt = fr >> 3, nt = fr & 7;
        const int q = lane >> 4, r15 = lane & 15;
        const int dl = nt*16 + r15;
        const int kb = mt*16 + q*4;
        lds[dl*33 + kb + 0] = v[i].x;
        lds[dl*33 + kb + 1] = v[i].y;
        lds[dl*33 + kb + 2] = v[i].z;
        lds[dl*33 + kb + 3] = v[i].w;
    }
    __syncthreads();

    float* outw = out + (size_t)b * (DD*KK) + jsl * 128 * KK;
    const float* Cw = Cg + jsl * 128 * KK;
#pragma unroll
    for (int i = 0; i < 4; ++i) {
        const int o4 = t + 256*i;
        const int dl = o4 >> 3, kq = (o4 & 7) * 4;
        const float4 c4 = *(const float4*)&Cw[dl*KK + kq];
        float4 rr;
        rr.x = lds[dl*33 + kq + 0] + asumT[kq + 0] * c4.x;
        rr.y = lds[dl*33 + kq + 1] + asumT[kq + 1] * c4.y;
        rr.z = lds[dl*33 + kq + 2] + asumT[kq + 2] * c4.z;
        rr.w = lds[dl*33 + kq + 3] + asumT[kq + 3] * c4.w;
        ((float4*)outw)[o4] = rr;
    }
}

extern "C" void kernel_launch(void* const* d_in, const int* in_sizes, int n_in,
                              void* d_out, int out_size, void* d_ws, size_t ws_size,
                              hipStream_t stream) {
    const float* x = (const float*)d_in[0];
    const float* W = (const float*)d_in[1];
    const float* C = (const float*)d_in[2];
    float* out = (float*)d_out;

    if (ws_size >= WS_NEED) {
        netvlad_stage1<true><<<dim3(NBLK), dim3(256), 0, stream>>>(x, W, C, out, d_ws);
        netvlad_stage2<<<dim3(NB * 4), dim3(256), 0, stream>>>(d_ws, C, out);
    } else {
        hipMemsetAsync(out, 0, (size_t)out_size * sizeof(float), stream);
        netvlad_stage1<false><<<dim3(NBLK), dim3(256), 0, stream>>>(x, W, C, out, d_ws);
    }
}

// Round 15
// 48.520 us; speedup vs baseline: 1.3002x; 1.0101x over previous
//
#include <hip/hip_runtime.h>

// NetVLAD fused via bf16 MFMA, two-stage, single-chunk blocks (5 barriers).
// R15 = R14 (xs 28 rows + bf16 spart -> 40.3 KB LDS, 4 blocks/CU) + spart
// zero-init so every OOB-reachable LDS byte is finite (R14 NaN'd on the
// uninitialized spart pad column hit by phase C's tolerated overrun).
//   s = x·W, a = softmax_k(s), v = a^T x + (sum a)·C
// x: [64,784,512] f32, W/C: [512,32] f32, out: [64, 512*32] f32
#define NB 64
#define HW 784
#define DD 512
#define KK 32
#define BPB 28            // blocks per batch (28 px each: 28*28 = 784 = HW)
#define PPB 28            // valid pixels per block
#define SLOTS 32          // logical px slots in MFMA (28 valid + 4 masked a=0)

typedef __attribute__((ext_vector_type(8))) short bf16x8;   // 8 bf16 (4 VGPR)
typedef __attribute__((ext_vector_type(4))) float f32x4;    // MFMA 16x16 acc
typedef __attribute__((ext_vector_type(4))) unsigned short u16x4;

// ws: bf16 partials [NB*BPB][4 waves][16 frags][64 lanes] u16x4 (8 B each),
//     then fp32 asums [NB*BPB][KK]
#define NBLK (NB * BPB)
#define PART_BYTES ((size_t)NBLK * 4 * 16 * 64 * 8)
#define WS_NEED    (PART_BYTES + (size_t)NBLK * KK * 4)

__device__ __forceinline__ unsigned short f2bf(float f) {
    unsigned u = __float_as_uint(f);
    u += 0x7fffu + ((u >> 16) & 1u);      // round-to-nearest-even
    return (unsigned short)(u >> 16);
}
__device__ __forceinline__ float bf2f(unsigned short u) {
    return __uint_as_float((unsigned)u << 16);
}
// packed f32x2 -> bf16x2, one instruction (lo = a, hi = b; T12 recipe)
__device__ __forceinline__ unsigned cvtpk(float a, float b) {
    unsigned r;
    asm("v_cvt_pk_bf16_f32 %0, %1, %2" : "=v"(r) : "v"(a), "v"(b));
    return r;
}

template <bool USE_WS>
__global__ __launch_bounds__(256) void netvlad_stage1(
    const float* __restrict__ x, const float* __restrict__ Wg,
    const float* __restrict__ Cg, float* __restrict__ out,
    void* __restrict__ ws)
{
    // LDS 40,256 B -> 4 blocks/CU (4 x 40,448 = 161,792 <= 163,840)
    __shared__ __align__(16) unsigned short xs[28 * 520];      // 29,120 B bf16
    __shared__ unsigned short spart[4][SLOTS][33];             // 8,448 B bf16 partials
    __shared__ __align__(16) unsigned short aTe[KK * 40];      // a^T [k][px] 2,560 B
    __shared__ float asumF[KK];

    const int tid = threadIdx.x;
    const int l   = tid & 63, w = tid >> 6;      // lane, wave 0..3 (= d-slice 128w)
    const int l15 = l & 15,  lq = l >> 4;        // frag row/col, quarter
    const int k   = tid & 31, pg = tid >> 5;     // softmax mapping: pg 0..7
    const int bid = blockIdx.x;
    const int b   = bid / BPB;
    const int pb  = (bid % BPB) * PPB;
    const float* xb = x + (size_t)b * HW * DD;

    // Zero-init spart: phase A/C deliberately read past xs into this region
    // (rows 28-31); every reachable byte must be finite. 2112 dwords total.
    {
        unsigned* sz = (unsigned*)spart;
#pragma unroll
        for (int i = 0; i < 8; ++i) sz[tid + 256*i] = 0u;
        if (tid < 2112 - 2048) sz[2048 + tid] = 0u;
    }

    // W B-frags: Wf[ks][nt] lane holds W[d = w*128+ks*32+lq*8+j][nt*16+l15]
    bf16x8 Wf[4][2];
#pragma unroll
    for (int ks = 0; ks < 4; ++ks)
#pragma unroll
        for (int nt = 0; nt < 2; ++nt)
#pragma unroll
            for (int j = 0; j < 8; ++j)
                Wf[ks][nt][j] = (short)f2bf(Wg[(w*128 + ks*32 + lq*8 + j) * KK + nt*16 + l15]);

    // phase-C acc: k = mt*16+lq*4+jj, d = w*128 + nt*16 + l15
    f32x4 acc[2][8];
#pragma unroll
    for (int mt = 0; mt < 2; ++mt)
#pragma unroll
        for (int nt = 0; nt < 8; ++nt)
#pragma unroll
            for (int jj = 0; jj < 4; ++jj) acc[mt][nt][jj] = 0.f;
    float asum_part = 0.f;

    // ---- stage: 28 px * 512 f32 -> bf16 LDS; 14 float4/thread, no clamp ----
#pragma unroll
    for (int h = 0; h < 2; ++h) {
        float4 r[7];
#pragma unroll
        for (int j = 0; j < 7; ++j) {
            const int f = tid + 256*(h*7 + j), row = f >> 7, c4 = f & 127;
            r[j] = *(const float4*)(xb + (size_t)(pb + row) * DD + c4*4);
        }
#pragma unroll
        for (int j = 0; j < 7; ++j) {
            const int f = tid + 256*(h*7 + j), row = f >> 7, c4 = f & 127;
            uint2 pk = make_uint2(cvtpk(r[j].x, r[j].y), cvtpk(r[j].z, r[j].w));
            *(uint2*)&xs[row*520 + c4*4] = pk;
        }
    }
    __syncthreads();

    // ---- phase A: s[32px][32k] partial over this wave's 128-d slice (16 MFMA)
    //      (mt=1 rows 28-31 read past xs into zero-inited spart: finite;
    //       their outputs are force-zeroed on write below) ----
    {
        f32x4 sp[2][2];
#pragma unroll
        for (int mt = 0; mt < 2; ++mt)
#pragma unroll
            for (int nt = 0; nt < 2; ++nt)
#pragma unroll
                for (int jj = 0; jj < 4; ++jj) sp[mt][nt][jj] = 0.f;
#pragma unroll
        for (int ks = 0; ks < 4; ++ks) {
            bf16x8 af[2];
#pragma unroll
            for (int mt = 0; mt < 2; ++mt)
                af[mt] = *(const bf16x8*)&xs[(mt*16 + l15)*520 + w*128 + ks*32 + lq*8];
#pragma unroll
            for (int mt = 0; mt < 2; ++mt)
#pragma unroll
                for (int nt = 0; nt < 2; ++nt)
                    sp[mt][nt] = __builtin_amdgcn_mfma_f32_16x16x32_bf16(
                        af[mt], Wf[ks][nt], sp[mt][nt], 0, 0, 0);
        }
        // bf16 partial store; rows p>=28 (mt==1 && lq==3) written as 0 (masked px)
        const bool padrow = (lq == 3);
#pragma unroll
        for (int mt = 0; mt < 2; ++mt)
#pragma unroll
            for (int nt = 0; nt < 2; ++nt)
#pragma unroll
                for (int jj = 0; jj < 4; ++jj) {
                    unsigned short v = f2bf(sp[mt][nt][jj]);
                    if (mt == 1 && padrow) v = 0;
                    spart[w][mt*16 + lq*4 + jj][nt*16 + l15] = v;
                }
    }
    __syncthreads();

    // ---- phase B: softmax over k; thread (pg,k), px = pg + 8i ----
#pragma unroll
    for (int i = 0; i < 4; ++i) {
        const int p = pg + 8*i;
        const float s = bf2f(spart[0][p][k]) + bf2f(spart[1][p][k])
                      + bf2f(spart[2][p][k]) + bf2f(spart[3][p][k]);
        const float e = __expf(s);
        float su = e;
#pragma unroll
        for (int msk = 16; msk >= 1; msk >>= 1)
            su += __shfl_xor(su, msk);
        const float a = (p < PPB) ? e * __builtin_amdgcn_rcpf(su) : 0.f;
        asum_part += a;
        aTe[k*40 + p] = f2bf(a);
    }
    __syncthreads();

    // ---- phase C: v^T[32k][128d-slice] += a^T[32k][32px] · x[32px][d] (16 MFMA)
    //      (rows 28-31 overrun into spart: all finite bf16 now, and a=0 there) ----
    {
        bf16x8 afr[2];
#pragma unroll
        for (int mt = 0; mt < 2; ++mt)
            afr[mt] = *(const bf16x8*)&aTe[(mt*16 + l15)*40 + lq*8];
#pragma unroll
        for (int nt = 0; nt < 8; ++nt) {
            const int d = w*128 + nt*16 + l15;
            bf16x8 bfr;
#pragma unroll
            for (int j = 0; j < 8; ++j) {                  // column read of x, j rotated
                const int jj = (j + 2*lq) & 7;             // per-quarter bank stagger
                bfr[jj] = (short)xs[(lq*8 + jj)*520 + d];
            }
#pragma unroll
            for (int mt = 0; mt < 2; ++mt)
                acc[mt][nt] = __builtin_amdgcn_mfma_f32_16x16x32_bf16(
                    afr[mt], bfr, acc[mt][nt], 0, 0, 0);
        }
    }
    __syncthreads();

    // ---- block asum[k] reduce (ared aliases aTe: dead after phase C) ----
    float* ared = (float*)aTe;     // [8][32]
    ared[pg*KK + k] = asum_part;
    __syncthreads();
    float* wsA = (float*)((char*)ws + PART_BYTES);
    if (tid < KK) {
        float s = 0.f;
#pragma unroll
        for (int g = 0; g < 8; ++g) s += ared[g*KK + tid];
        if (USE_WS) wsA[(size_t)bid * KK + tid] = s;
        else        asumF[tid] = s;
    }

    if (USE_WS) {
        // bf16 partial store, thread-major: coalesced 8B streaming (cvt_pk packed)
        u16x4* o = (u16x4*)ws + ((size_t)bid * 4 + w) * (16 * 64);
#pragma unroll
        for (int mt = 0; mt < 2; ++mt)
#pragma unroll
            for (int nt = 0; nt < 8; ++nt) {
                uint2 pk = make_uint2(cvtpk(acc[mt][nt][0], acc[mt][nt][1]),
                                      cvtpk(acc[mt][nt][2], acc[mt][nt][3]));
                *(uint2*)&o[(mt*8 + nt)*64 + l] = pk;
            }
    } else {
        __syncthreads();
        float* ob = out + (size_t)b * (DD * KK);
#pragma unroll
        for (int mt = 0; mt < 2; ++mt)
#pragma unroll
            for (int nt = 0; nt < 8; ++nt)
#pragma unroll
                for (int jj = 0; jj < 4; ++jj) {
                    const int kk = mt*16 + lq*4 + jj;
                    const int d  = w*128 + nt*16 + l15;
                    atomicAdd(&ob[d*KK + kk], acc[mt][nt][jj] + asumF[kk] * Cg[d*KK + kk]);
                }
    }
}

// Stage 2: block = (b, 128-d slice jsl): sum 28 bf16 partials, add asum*C, write
__global__ __launch_bounds__(256) void netvlad_stage2(
    const void* __restrict__ ws, const float* __restrict__ Cg,
    float* __restrict__ out)
{
    __shared__ float lds[128 * 33];    // canonical [d_local][k], padded
    __shared__ float asumT[KK];

    const int t = threadIdx.x;
    const int b = blockIdx.x >> 2;
    const int jsl = blockIdx.x & 3;    // = stage1 wave index (d-slice 128*jsl)

    const float* wsA = (const float*)((const char*)ws + PART_BYTES);
    if (t < KK) {
        float s = 0.f;
#pragma unroll
        for (int p = 0; p < BPB; ++p)
            s += wsA[(size_t)(b*BPB + p) * KK + t];
        asumT[t] = s;
    }

    const u16x4* wsp = (const u16x4*)ws;
    float4 v[4];
#pragma unroll
    for (int i = 0; i < 4; ++i) v[i] = make_float4(0.f, 0.f, 0.f, 0.f);
    for (int p = 0; p < BPB; ++p) {
        const size_t base = ((size_t)(b*BPB + p) * 4 + jsl) * (16 * 64);
#pragma unroll
        for (int i = 0; i < 4; ++i) {
            const u16x4 u = wsp[base + t + 256*i];
            v[i].x += bf2f(u[0]); v[i].y += bf2f(u[1]);
            v[i].z += bf2f(u[2]); v[i].w += bf2f(u[3]);
        }
    }
    // scatter frag layout -> canonical [d_local][k]
#pragma unroll
    for (int i = 0; i < 4; ++i) {
        const int flat = t + 256*i;               // fr*64 + lane
        const int fr = flat >> 6, lane = flat & 63;
        const int mt = fr >> 3, nt = fr & 7;
        const int q = lane >> 4, r15 = lane & 15;
        const int dl = nt*16 + r15;
        const int kb = mt*16 + q*4;
        lds[dl*33 + kb + 0] = v[i].x;
        lds[dl*33 + kb + 1] = v[i].y;
        lds[dl*33 + kb + 2] = v[i].z;
        lds[dl*33 + kb + 3] = v[i].w;
    }
    __syncthreads();

    float* outw = out + (size_t)b * (DD*KK) + jsl * 128 * KK;
    const float* Cw = Cg + jsl * 128 * KK;
#pragma unroll
    for (int i = 0; i < 4; ++i) {
        const int o4 = t + 256*i;
        const int dl = o4 >> 3, kq = (o4 & 7) * 4;
        const float4 c4 = *(const float4*)&Cw[dl*KK + kq];
        float4 rr;
        rr.x = lds[dl*33 + kq + 0] + asumT[kq + 0] * c4.x;
        rr.y = lds[dl*33 + kq + 1] + asumT[kq + 1] * c4.y;
        rr.z = lds[dl*33 + kq + 2] + asumT[kq + 2] * c4.z;
        rr.w = lds[dl*33 + kq + 3] + asumT[kq + 3] * c4.w;
        ((float4*)outw)[o4] = rr;
    }
}

extern "C" void kernel_launch(void* const* d_in, const int* in_sizes, int n_in,
                              void* d_out, int out_size, void* d_ws, size_t ws_size,
                              hipStream_t stream) {
    const float* x = (const float*)d_in[0];
    const float* W = (const float*)d_in[1];
    const float* C = (const float*)d_in[2];
    float* out = (float*)d_out;

    if (ws_size >= WS_NEED) {
        netvlad_stage1<true><<<dim3(NBLK), dim3(256), 0, stream>>>(x, W, C, out, d_ws);
        netvlad_stage2<<<dim3(NB * 4), dim3(256), 0, stream>>>(d_ws, C, out);
    } else {
        hipMemsetAsync(out, 0, (size_t)out_size * sizeof(float), stream);
        netvlad_stage1<false><<<dim3(NBLK), dim3(256), 0, stream>>>(x, W, C, out, d_ws);
    }
}